// Round 3
// baseline (107.778 us; speedup 1.0000x reference)
//
#include <hip/hip_runtime.h>

// CIN fully fused, d-contraction-first. R10 (resubmit; previous run died on
// container infra, not kernel): break the 1-block/CU phase serialization.
// G=4 per block, 512 threads (8 waves), ~71KB LDS -> TWO independent blocks
// per CU. Same 16 waves/CU as R9, but the two blocks' phases interleave
// (one computes while the other drains barriers/loads). Phase 3 C-cols are
// g=col<4 -> direct float4 global store, no S32 LDS roundtrip, one fewer
// barrier.
//   out1[b,h] = sum_d h1[b,h,d];  h1 = sum_{f,q} W0[h,fq] x[b,f,d] x[b,q,d]
//   out2[b,h] = sum_p W1[h,p] U[b,p];  U[b,(f,q)] = sum_d x[b,f,d] h1[b,q,d]
// 512 blocks x 512 thr.
//   phase 1: wave = (gp, mt); 3 chained 32x32x16 MFMAs per f, fp32 sx scale
//   phase 2b: wave = (g, qh); writes Ub2[f][g][q], imm-offset b16 stores
//   phase 3: wave = t; full cb range, 2-cb-ahead W prefetch, float4 store

#define F0   39
#define D_   16
#define H_   128
#define P0_  1521
#define P1_  4992
#define G4   4
#define NF1  (F0 * 3 * 4)   // 468 layer-1 A-frags (f x ks x mt), 32x32x16
#define NF2  (F0 * 4 * 8)   // 1248 W1 A-frags (16x16x32)
#define SROW 72             // S_bf row stride in shorts (144B, 16B-aligned)
#define UGS  136            // Ub2 g-stride in shorts (272B: dw%32 = 4)
#define UFS  552            // Ub2 f-stride in shorts (4*136+8; 1104B, 16B-aligned)

typedef __attribute__((ext_vector_type(8)))  short   short8;
typedef __attribute__((ext_vector_type(8)))  __bf16  bf16x8;
typedef __attribute__((ext_vector_type(4)))  float   floatx4;
typedef __attribute__((ext_vector_type(16))) float   floatx16;

__device__ __forceinline__ unsigned short bf16rne(float f) {
  unsigned int u = __float_as_uint(f);
  u += 0x7FFFu + ((u >> 16) & 1u);
  return (unsigned short)(u >> 16);
}

__device__ __forceinline__ floatx4 mfma16(short8 a, short8 b, floatx4 c) {
  return __builtin_amdgcn_mfma_f32_16x16x32_bf16(
      __builtin_bit_cast(bf16x8, a), __builtin_bit_cast(bf16x8, b), c, 0, 0, 0);
}

__device__ __forceinline__ floatx16 mfma32(short8 a, short8 b, floatx16 c) {
  return __builtin_amdgcn_mfma_f32_32x32x16_bf16(
      __builtin_bit_cast(bf16x8, a), __builtin_bit_cast(bf16x8, b), c, 0, 0, 0);
}

// ---------- pack W into MFMA A-frag order (unchanged from R9) ----------
// wA1 (32x32x16): frag = (f*3 + ks)*4 + mt
//   A[m][k]: m = mt*32 + (lane&31), k = (lane>>5)*8 + j, q = ks*16 + k
// wA2 (16x16x32): frag = (f*4 + s)*8 + t
__global__ __launch_bounds__(256) void pack_w_kernel(const float* __restrict__ w0,
                                                     const float* __restrict__ w1,
                                                     short8* __restrict__ wA1,
                                                     short8* __restrict__ wA2) {
  int id = blockIdx.x * 256 + threadIdx.x;
  union { short8 v; unsigned short e[8]; } pk;
  if (id < NF1 * 64) {
    int lane = id & 63, frag = id >> 6;
    int mt = frag & 3, fks = frag >> 2;
    int f = fks / 3, ks = fks - f * 3;
    int m = mt * 32 + (lane & 31);
    int q0 = ks * 16 + (lane >> 5) * 8;
#pragma unroll
    for (int j = 0; j < 8; ++j) {
      int q = q0 + j;
      pk.e[j] = (q < F0) ? bf16rne(w0[(size_t)m * P0_ + f * F0 + q]) : (unsigned short)0;
    }
    wA1[frag * 64 + lane] = pk.v;
  } else if (id < (NF1 + NF2) * 64) {
    int u = id - NF1 * 64;
    int lane = u & 63, frag = u >> 6;
    int t = frag & 7, s = (frag >> 3) & 3, f = frag >> 5;
    int m = t * 16 + (lane & 15);
    int pb = f * 128 + s * 32 + (lane >> 4) * 8;
#pragma unroll
    for (int j = 0; j < 8; ++j) pk.e[j] = bf16rne(w1[(size_t)m * P1_ + pb + j]);
    wA2[frag * 64 + lane] = pk.v;
  }
}

// ---------- fused main kernel ----------
__global__ __launch_bounds__(512, 4) void cin_fused(const float* __restrict__ x,
                                                    const short8* __restrict__ wA1,
                                                    const short8* __restrict__ wA2,
                                                    float* __restrict__ out) {
  // LDS: [0, 9984) xs fp32
  //      [9984, +18432) S_bf [128][SROW] | [28416, +43056) xTb then Ub2 (aliased)
  __shared__ __align__(16) char smem[9984 + 128 * SROW * 2 + F0 * UFS * 2];
  float (*xs)[F0][D_]   = (float (*)[F0][D_])smem;
  unsigned short* S_bf  = (unsigned short*)(smem + 9984);             // [128][SROW]
  unsigned short* xTb   = (unsigned short*)(smem + 9984 + 128 * SROW * 2);
  unsigned short* Ub2   = xTb;                                        // aliased

  const int tid  = threadIdx.x;
  const int lane = tid & 63;
  const int wv   = tid >> 6;      // 8 waves
  const int col  = lane & 15;
  const int quad = lane >> 4;
  const int b0   = blockIdx.x * G4;
  const floatx4 zf4 = {0.f, 0.f, 0.f, 0.f};

  // ---- stage x (coalesced float4) ----
  {
    const float4* xg = (const float4*)(x + (size_t)b0 * (F0 * D_));
    float4* xl = (float4*)smem;
    for (int i = tid; i < G4 * F0 * D_ / 4; i += 512) xl[i] = xg[i];
  }
  __syncthreads();

  // ---- xTb[g][q8][d][j] = bf16(x[g][q8*8+j][d]), zero-pad q>=39 ----
  {
    int i = tid;                      // exactly 512 = G4*8*16 entries
    int d = i & 15, q8 = (i >> 4) & 7, g = i >> 7;
    union { short8 v; unsigned short e[8]; } pk;
#pragma unroll
    for (int j = 0; j < 8; ++j) {
      int q = q8 * 8 + j;
      pk.e[j] = (q < F0) ? bf16rne(xs[g][q][d]) : (unsigned short)0;
    }
    *(short8*)&xTb[(size_t)i * 8] = pk.v;
  }
  __syncthreads();

  // ===== phase 1: 32x32x16; wave = (gp, mt). C[m=h32][n=(g_lo,d)] =====
  //   per f: acf = sum_{q<48} W0[h, f*39+q] * x[g,q,d]; acc += acf * x[g,f,d]
  {
    const int mt  = wv & 3;          // h-tile of 32
    const int gp  = wv >> 2;         // batch pair: g = gp*2 + (c32>>4)
    const int c32 = lane & 31;       // C col: n = g_local*16 + d
    const int kg  = lane >> 5;       // k half (8 q's each)
    const int g   = gp * 2 + (c32 >> 4);
    const int d   = c32 & 15;

    // B[n][k]: n = c32, k = kg*8+j, q = ks*16 + k  ->  xTb[g][ks*2+kg][d][j]
    short8 bq0 = *(const short8*)&xTb[(size_t)(((g * 8 + 0 + kg) * 16) + d) * 8];
    short8 bq1 = *(const short8*)&xTb[(size_t)(((g * 8 + 2 + kg) * 16) + d) * 8];
    short8 bq2 = *(const short8*)&xTb[(size_t)(((g * 8 + 4 + kg) * 16) + d) * 8];

    floatx16 acc = {0.f, 0.f, 0.f, 0.f, 0.f, 0.f, 0.f, 0.f,
                    0.f, 0.f, 0.f, 0.f, 0.f, 0.f, 0.f, 0.f};
    const floatx16 zf16 = acc;

    // 2-f-ahead A prefetch
    short8 a0 = wA1[(size_t)(0 * 4 + mt) * 64 + lane];
    short8 a1 = wA1[(size_t)(1 * 4 + mt) * 64 + lane];
    short8 a2 = wA1[(size_t)(2 * 4 + mt) * 64 + lane];
    short8 b0f = wA1[(size_t)(3 * 4 + mt) * 64 + lane];
    short8 b1f = wA1[(size_t)(4 * 4 + mt) * 64 + lane];
    short8 b2f = wA1[(size_t)(5 * 4 + mt) * 64 + lane];
    for (int f = 0; f < F0; ++f) {
      const int f2 = (f + 2 < F0) ? f + 2 : F0 - 1;
      short8 n0 = wA1[(size_t)((f2 * 3 + 0) * 4 + mt) * 64 + lane];
      short8 n1 = wA1[(size_t)((f2 * 3 + 1) * 4 + mt) * 64 + lane];
      short8 n2 = wA1[(size_t)((f2 * 3 + 2) * 4 + mt) * 64 + lane];
      floatx16 acf = mfma32(a0, bq0, zf16);
      acf = mfma32(a1, bq1, acf);
      acf = mfma32(a2, bq2, acf);
      const float sx = xs[g][f][d];
      acc += acf * sx;
      a0 = b0f; a1 = b1f; a2 = b2f;
      b0f = n0; b1f = n1; b2f = n2;
    }
    // h1 -> S_bf (bf16). Row = h = mt*32 + ((r&3)+8*(r>>2)+4*kg), col = g*16+d.
    // lanes 0-31 hit banks 0-15, lanes 32-63 banks 16-31: 2-way = free.
#pragma unroll
    for (int r = 0; r < 16; ++r) {
      const int row = (r & 3) + 8 * (r >> 2) + 4 * kg;
      S_bf[(size_t)(mt * 32 + row) * SROW + gp * 32 + c32] = bf16rne(acc[r]);
    }
  }
  __syncthreads();

  // ===== phase 2a: out1[b,h] = sum_d h1 (512 threads, one shot) =====
  {
    int h = tid & 127, g = tid >> 7;
    union { short8 v; unsigned int u[4]; } w0v, w1v;
    w0v.v = *(const short8*)&S_bf[(size_t)h * SROW + g * 16];
    w1v.v = *(const short8*)&S_bf[(size_t)h * SROW + g * 16 + 8];
    float sum = 0.f;
#pragma unroll
    for (int p = 0; p < 4; ++p) {
      sum += __uint_as_float(w0v.u[p] << 16) + __uint_as_float(w0v.u[p] & 0xFFFF0000u);
      sum += __uint_as_float(w1v.u[p] << 16) + __uint_as_float(w1v.u[p] & 0xFFFF0000u);
    }
    out[(size_t)(b0 + g) * 256 + h] = sum;
  }

  // ===== phase 2b: wave = (g, qh). U[g,(f,q)] = sum_d x[g,f,d] h1[g,q,d] =====
  // MFMA: A[m=f][k=d], B[n=q][k=d] -> C[m=f][n=q].
  // Store to Ub2[f][g][q]: imm-offset b16 stores, <=2-way banks.
  {
    const int g  = wv & 3;
    const int qh = wv >> 2;
    short8 af[3];
#pragma unroll
    for (int ft = 0; ft < 3; ++ft) {
      union { short8 v; unsigned short e[8]; } pk;
      int f = ft * 16 + col;
      if (quad < 2 && f < F0) {
        const float* xp = &xs[g][f][quad * 8];
#pragma unroll
        for (int j = 0; j < 8; ++j) pk.e[j] = bf16rne(xp[j]);
      } else {
#pragma unroll
        for (int j = 0; j < 8; ++j) pk.e[j] = 0;
      }
      af[ft] = pk.v;
    }
#pragma unroll
    for (int qi = 0; qi < 4; ++qi) {
      const int qt = qh * 4 + qi;
      short8 bq;
      if (quad < 2) {
        bq = *(const short8*)&S_bf[(size_t)(qt * 16 + col) * SROW + g * 16 + quad * 8];
      } else {
        bq = short8{0, 0, 0, 0, 0, 0, 0, 0};
      }
#pragma unroll
      for (int ft = 0; ft < 3; ++ft) {
        floatx4 c2 = mfma16(af[ft], bq, zf4);
        unsigned short* up =
            &Ub2[(size_t)(ft * 16 + quad * 4) * UFS + g * UGS + qt * 16 + col];
        if (ft < 2) {
#pragma unroll
          for (int r = 0; r < 4; ++r) up[r * UFS] = bf16rne(c2[r]);
        } else {
#pragma unroll
          for (int r = 0; r < 4; ++r)
            if (32 + quad * 4 + r < F0) up[r * UFS] = bf16rne(c2[r]);
        }
      }
    }
  }
  __syncthreads();

  // ===== phase 3: wave = t. out2 = sum_c W1frag(c) x Ufrag(c) =====
  // B-frag: k = quad*8+j over p = cb*128 + i*32 + k -> Ub2[cb][g=col][i*32+quad*8..+8]
  // W-frag prefetch 2 cb ahead. C[m=h][n=g]: direct float4 store, no LDS reduce.
  {
    const int t = wv;
    const short8 zero8 = {0, 0, 0, 0, 0, 0, 0, 0};
    floatx4 aco[4];
#pragma unroll
    for (int i = 0; i < 4; ++i) aco[i] = zf4;
    short8 aW[4], aX[4];
#pragma unroll
    for (int i = 0; i < 4; ++i)
      aW[i] = wA2[(size_t)((0 * 4 + i) * 8 + t) * 64 + lane];
#pragma unroll
    for (int i = 0; i < 4; ++i)
      aX[i] = wA2[(size_t)((1 * 4 + i) * 8 + t) * 64 + lane];
    for (int cb = 0; cb < F0; ++cb) {
      const int c2 = (cb + 2 < F0) ? cb + 2 : F0 - 1;
      short8 nx[4];
#pragma unroll
      for (int i = 0; i < 4; ++i)
        nx[i] = wA2[(size_t)((c2 * 4 + i) * 8 + t) * 64 + lane];
      const unsigned short* ubase = &Ub2[(size_t)cb * UFS + col * UGS + quad * 8];
#pragma unroll
      for (int i = 0; i < 4; ++i) {
        short8 bU = (col < 4) ? *(const short8*)(ubase + i * 32) : zero8;
        aco[i] = mfma16(aW[i], bU, aco[i]);
      }
#pragma unroll
      for (int i = 0; i < 4; ++i) { aW[i] = aX[i]; aX[i] = nx[i]; }
    }
    if (col < 4) {
      float4 o;
      o.x = (aco[0][0] + aco[1][0]) + (aco[2][0] + aco[3][0]);
      o.y = (aco[0][1] + aco[1][1]) + (aco[2][1] + aco[3][1]);
      o.z = (aco[0][2] + aco[1][2]) + (aco[2][2] + aco[3][2]);
      o.w = (aco[0][3] + aco[1][3]) + (aco[2][3] + aco[3][3]);
      // h = t*16 + quad*4 + r; r contiguous -> aligned float4
      *(float4*)&out[(size_t)(b0 + col) * 256 + 128 + t * 16 + quad * 4] = o;
    }
  }
}

// ---------- fp32 last-resort fallback ----------
__global__ __launch_bounds__(128) void cin_fused_fallback(const float* __restrict__ x,
                                                          const float* __restrict__ w0,
                                                          const float* __restrict__ w1,
                                                          float* __restrict__ out) {
  __shared__ float4 xs4[F0 * D_ / 4];
  __shared__ float4 h1s4[H_ * D_ / 4];
  __shared__ float4 z4[H_ * D_ / 4];
  const int tid = threadIdx.x;
  const int b = blockIdx.x;
  const int hh = tid >> 2, dd = tid & 3, h0 = hh << 2;
  {
    const float4* xg = (const float4*)(x + (size_t)b * (F0 * D_));
    for (int i = tid; i < F0 * D_ / 4; i += 128) xs4[i] = xg[i];
  }
  __syncthreads();
  float acc[4][4];
#pragma unroll
  for (int i = 0; i < 4; ++i)
#pragma unroll
    for (int j = 0; j < 4; ++j) acc[i][j] = 0.f;
  for (int f = 0; f < F0; ++f) {
    for (int i = tid; i < F0 * D_ / 4; i += 128) {
      float4 xv = xs4[(f << 2) + (i & 3)], qv = xs4[i];
      z4[i] = make_float4(xv.x * qv.x, xv.y * qv.y, xv.z * qv.z, xv.w * qv.w);
    }
    __syncthreads();
    for (int q = 0; q < F0; ++q) {
      float4 zv = z4[(q << 2) + dd];
      int p = f * F0 + q;
      float ww[4] = {w0[(h0 + 0) * P0_ + p], w0[(h0 + 1) * P0_ + p],
                     w0[(h0 + 2) * P0_ + p], w0[(h0 + 3) * P0_ + p]};
      float zz[4] = {zv.x, zv.y, zv.z, zv.w};
#pragma unroll
      for (int hi = 0; hi < 4; ++hi)
#pragma unroll
        for (int di = 0; di < 4; ++di) acc[hi][di] += ww[hi] * zz[di];
    }
    __syncthreads();
  }
#pragma unroll
  for (int hi = 0; hi < 4; ++hi)
    h1s4[(h0 + hi) * 4 + dd] = make_float4(acc[hi][0], acc[hi][1], acc[hi][2], acc[hi][3]);
  __syncthreads();
  {
    float4 a0 = h1s4[tid * 4 + 0], a1 = h1s4[tid * 4 + 1];
    float4 a2 = h1s4[tid * 4 + 2], a3 = h1s4[tid * 4 + 3];
    out[(size_t)b * 256 + tid] = (a0.x + a0.y + a0.z + a0.w) + (a1.x + a1.y + a1.z + a1.w) +
                                 (a2.x + a2.y + a2.z + a2.w) + (a3.x + a3.y + a3.z + a3.w);
  }
#pragma unroll
  for (int i = 0; i < 4; ++i)
#pragma unroll
    for (int j = 0; j < 4; ++j) acc[i][j] = 0.f;
  for (int f = 0; f < F0; ++f) {
    for (int i = tid; i < H_ * D_ / 4; i += 128) {
      float4 xv = xs4[(f << 2) + (i & 3)], hv = h1s4[i];
      z4[i] = make_float4(xv.x * hv.x, xv.y * hv.y, xv.z * hv.z, xv.w * hv.w);
    }
    __syncthreads();
    for (int q = 0; q < H_; ++q) {
      float4 zv = z4[(q << 2) + dd];
      int p = f * H_ + q;
      float ww[4] = {w1[(h0 + 0) * P1_ + p], w1[(h0 + 1) * P1_ + p],
                     w1[(h0 + 2) * P1_ + p], w1[(h0 + 3) * P1_ + p]};
      float zz[4] = {zv.x, zv.y, zv.z, zv.w};
#pragma unroll
      for (int hi = 0; hi < 4; ++hi)
#pragma unroll
        for (int di = 0; di < 4; ++di) acc[hi][di] += ww[hi] * zz[di];
    }
    __syncthreads();
  }
#pragma unroll
  for (int hi = 0; hi < 4; ++hi)
    z4[(h0 + hi) * 4 + dd] = make_float4(acc[hi][0], acc[hi][1], acc[hi][2], acc[hi][3]);
  __syncthreads();
  {
    float4 a0 = z4[tid * 4 + 0], a1 = z4[tid * 4 + 1];
    float4 a2 = z4[tid * 4 + 2], a3 = z4[tid * 4 + 3];
    out[(size_t)b * 256 + 128 + tid] = (a0.x + a0.y + a0.z + a0.w) + (a1.x + a1.y + a1.z + a1.w) +
                                       (a2.x + a2.y + a2.z + a2.w) + (a3.x + a3.y + a3.z + a3.w);
  }
}

extern "C" void kernel_launch(void* const* d_in, const int* in_sizes, int n_in,
                              void* d_out, int out_size, void* d_ws, size_t ws_size,
                              hipStream_t stream) {
  const float* x  = (const float*)d_in[0];
  const float* w0 = (const float*)d_in[1];
  const float* w1 = (const float*)d_in[2];
  float* out = (float*)d_out;

  const size_t nfr    = (size_t)(NF1 + NF2) * 64;   // 109824 (frag,lane) pairs
  const size_t wbytes = nfr * sizeof(short8);       // ~1.76 MB

  if (ws_size >= wbytes) {
    short8* wA1 = (short8*)d_ws;
    short8* wA2 = wA1 + (size_t)NF1 * 64;
    pack_w_kernel<<<(int)((nfr + 255) / 256), 256, 0, stream>>>(w0, w1, wA1, wA2);
    cin_fused<<<512, 512, 0, stream>>>(x, wA1, wA2, out);
  } else {
    cin_fused_fallback<<<2048, 128, 0, stream>>>(x, w0, w1, out);
  }
}

// Round 4
// 95.629 us; speedup vs baseline: 1.1270x; 1.1270x over previous
//
#include <hip/hip_runtime.h>

// CIN fully fused, d-contraction-first. R11: back to G=8 / 1024-thr / 1
// block/CU (R9's minimal per-CU W traffic — R10 proved traffic, not
// barriers, binds), and halve the duplicated phase-1 wA1 stream:
// wave = (fh2, gp2, mt) — each wave covers half the f range but TWO gp
// C-tiles, so each A-frag load feeds 2 MFMA chains (dup 4x -> 2x).
// f-half partials exchanged via a 32KB LDS buffer (aliased into dead xTb
// space), summed in fp32, single final S_bf store. Plus: phase-1 A-ring
// issued at kernel top (hidden under x-staging), phase-3 first W loads
// issued before the 2b->3 barrier (drain completes them for free).
//   out1[b,h] = sum_d h1[b,h,d];  h1 = sum_{f,q} W0[h,fq] x[b,f,d] x[b,q,d]
//   out2[b,h] = sum_p W1[h,p] U[b,p];  U[b,(f,q)] = sum_d x[b,f,d] h1[b,q,d]
// 256 blocks x 1024 thr, ~140KB LDS.

#define F0   39
#define D_   16
#define H_   128
#define P0_  1521
#define P1_  4992
#define G8   8
#define NF1  (F0 * 3 * 4)   // 468 layer-1 A-frags (f x ks x mt), 32x32x16
#define NF2  (F0 * 4 * 8)   // 1248 W1 A-frags (16x16x32)
#define SROW 136            // S_bf row stride in shorts (272B, 16B-aligned)
#define UGS  136            // Ub2 g-stride in shorts (272B: dw%32 = 4)
#define UFS  1096           // Ub2 f-stride in shorts (8*136+8; 2192B, 16B-aligned)

#define SBF_OFF   19968                    // xs = [0, 19968)
#define R_OFF     (SBF_OFF + 128 * SROW * 2)   // 54784: xTb / Ub2 region
#define XCH_OFF   (R_OFF + 16384)          // 71168: exchange buf (32KB), after xTb
#define SMEM_SZ   (R_OFF + F0 * UFS * 2)   // 140272

typedef __attribute__((ext_vector_type(8)))  short   short8;
typedef __attribute__((ext_vector_type(8)))  __bf16  bf16x8;
typedef __attribute__((ext_vector_type(4)))  float   floatx4;
typedef __attribute__((ext_vector_type(16))) float   floatx16;

__device__ __forceinline__ unsigned short bf16rne(float f) {
  unsigned int u = __float_as_uint(f);
  u += 0x7FFFu + ((u >> 16) & 1u);
  return (unsigned short)(u >> 16);
}

__device__ __forceinline__ float bf16tof(unsigned short s) {
  return __uint_as_float((unsigned int)s << 16);
}

__device__ __forceinline__ floatx4 mfma16(short8 a, short8 b, floatx4 c) {
  return __builtin_amdgcn_mfma_f32_16x16x32_bf16(
      __builtin_bit_cast(bf16x8, a), __builtin_bit_cast(bf16x8, b), c, 0, 0, 0);
}

__device__ __forceinline__ floatx16 mfma32(short8 a, short8 b, floatx16 c) {
  return __builtin_amdgcn_mfma_f32_32x32x16_bf16(
      __builtin_bit_cast(bf16x8, a), __builtin_bit_cast(bf16x8, b), c, 0, 0, 0);
}

// ---------- pack W into MFMA A-frag order (unchanged) ----------
// wA1 (32x32x16): frag = (f*3 + ks)*4 + mt
//   A[m][k]: m = mt*32 + (lane&31), k = (lane>>5)*8 + j, q = ks*16 + k
// wA2 (16x16x32): frag = (f*4 + s)*8 + t
__global__ __launch_bounds__(256) void pack_w_kernel(const float* __restrict__ w0,
                                                     const float* __restrict__ w1,
                                                     short8* __restrict__ wA1,
                                                     short8* __restrict__ wA2) {
  int id = blockIdx.x * 256 + threadIdx.x;
  union { short8 v; unsigned short e[8]; } pk;
  if (id < NF1 * 64) {
    int lane = id & 63, frag = id >> 6;
    int mt = frag & 3, fks = frag >> 2;
    int f = fks / 3, ks = fks - f * 3;
    int m = mt * 32 + (lane & 31);
    int q0 = ks * 16 + (lane >> 5) * 8;
#pragma unroll
    for (int j = 0; j < 8; ++j) {
      int q = q0 + j;
      pk.e[j] = (q < F0) ? bf16rne(w0[(size_t)m * P0_ + f * F0 + q]) : (unsigned short)0;
    }
    wA1[frag * 64 + lane] = pk.v;
  } else if (id < (NF1 + NF2) * 64) {
    int u = id - NF1 * 64;
    int lane = u & 63, frag = u >> 6;
    int t = frag & 7, s = (frag >> 3) & 3, f = frag >> 5;
    int m = t * 16 + (lane & 15);
    int pb = f * 128 + s * 32 + (lane >> 4) * 8;
#pragma unroll
    for (int j = 0; j < 8; ++j) pk.e[j] = bf16rne(w1[(size_t)m * P1_ + pb + j]);
    wA2[frag * 64 + lane] = pk.v;
  }
}

// ---------- fused main kernel ----------
__global__ __launch_bounds__(1024, 4) void cin_fused(const float* __restrict__ x,
                                                     const short8* __restrict__ wA1,
                                                     const short8* __restrict__ wA2,
                                                     float* __restrict__ out) {
  // LDS: [0,19968) xs fp32 (reused as S32 in phase-3 reduce)
  //      [19968, +34816) S_bf
  //      [54784, +85488) xTb (16KB, dies after phase-1 bq reads)
  //                      Xch @ +16384 (32KB, phase-1 partial exchange)
  //                      Ub2 (phase 2b/3; aliases both)
  __shared__ __align__(16) char smem[SMEM_SZ];
  float (*xs)[F0][D_]   = (float (*)[F0][D_])smem;
  float* S32            = (float*)smem;                       // phase 3 only
  unsigned short* S_bf  = (unsigned short*)(smem + SBF_OFF);  // [128][SROW]
  unsigned short* xTb   = (unsigned short*)(smem + R_OFF);
  unsigned short* Ub2   = xTb;                                // aliased
  short8*        Xch    = (short8*)(smem + XCH_OFF);

  const int tid  = threadIdx.x;
  const int lane = tid & 63;
  const int wv   = tid >> 6;      // 16 waves
  const int col  = lane & 15;
  const int quad = lane >> 4;
  const int b0   = blockIdx.x * G8;
  const floatx4 zf4 = {0.f, 0.f, 0.f, 0.f};

  // ---- phase-1 wave coords (early, for top-of-kernel A prefetch) ----
  const int mt  = wv & 3;          // h-tile of 32
  const int gp2 = (wv >> 2) & 1;   // gp pair selector: gp in {gp2*2, gp2*2+1}
  const int fh2 = wv >> 3;         // f-half
  const int fB  = fh2 ? 20 : 0;
  const int fE  = fh2 ? F0 : 20;

  // issue the first two f's A-frags now; latency hides under x staging
  short8 a0 = wA1[(size_t)((fB * 3 + 0) * 4 + mt) * 64 + lane];
  short8 a1 = wA1[(size_t)((fB * 3 + 1) * 4 + mt) * 64 + lane];
  short8 a2 = wA1[(size_t)((fB * 3 + 2) * 4 + mt) * 64 + lane];
  short8 p0 = wA1[(size_t)(((fB + 1) * 3 + 0) * 4 + mt) * 64 + lane];
  short8 p1 = wA1[(size_t)(((fB + 1) * 3 + 1) * 4 + mt) * 64 + lane];
  short8 p2 = wA1[(size_t)(((fB + 1) * 3 + 2) * 4 + mt) * 64 + lane];

  // ---- stage x (coalesced float4) ----
  {
    const float4* xg = (const float4*)(x + (size_t)b0 * (F0 * D_));
    float4* xl = (float4*)smem;
    for (int i = tid; i < G8 * F0 * D_ / 4; i += 1024) xl[i] = xg[i];
  }
  __syncthreads();

  // ---- xTb[g][q8][d][j] = bf16(x[g][q8*8+j][d]), zero-pad q>=39 ----
  {
    int i = tid;                      // exactly 1024 = G8*8*16 entries
    int d = i & 15, q8 = (i >> 4) & 7, g = i >> 7;
    union { short8 v; unsigned short e[8]; } pk;
#pragma unroll
    for (int j = 0; j < 8; ++j) {
      int q = q8 * 8 + j;
      pk.e[j] = (q < F0) ? bf16rne(xs[g][q][d]) : (unsigned short)0;
    }
    *(short8*)&xTb[(size_t)i * 8] = pk.v;
  }
  __syncthreads();

  // ===== phase 1: 32x32x16; wave = (fh2, gp2, mt). Two gp C-tiles per =====
  // wave -> each A-frag load feeds 2 MFMA chains (wA1 dup 4x -> 2x).
  {
    const int c32 = lane & 31;       // C col: n = g_local*16 + d
    const int kg  = lane >> 5;       // k half (8 q's each)
    const int d   = c32 & 15;
    const int gA  = (gp2 * 2 + 0) * 2 + (c32 >> 4);
    const int gB  = (gp2 * 2 + 1) * 2 + (c32 >> 4);

    // B[n][k]: n = c32, k = kg*8+j, q = ks*16 + k  ->  xTb[g][ks*2+kg][d][j]
    short8 bqA0 = *(const short8*)&xTb[(size_t)(((gA * 8 + 0 + kg) * 16) + d) * 8];
    short8 bqA1 = *(const short8*)&xTb[(size_t)(((gA * 8 + 2 + kg) * 16) + d) * 8];
    short8 bqA2 = *(const short8*)&xTb[(size_t)(((gA * 8 + 4 + kg) * 16) + d) * 8];
    short8 bqB0 = *(const short8*)&xTb[(size_t)(((gB * 8 + 0 + kg) * 16) + d) * 8];
    short8 bqB1 = *(const short8*)&xTb[(size_t)(((gB * 8 + 2 + kg) * 16) + d) * 8];
    short8 bqB2 = *(const short8*)&xTb[(size_t)(((gB * 8 + 4 + kg) * 16) + d) * 8];

    floatx16 accA = {0.f, 0.f, 0.f, 0.f, 0.f, 0.f, 0.f, 0.f,
                     0.f, 0.f, 0.f, 0.f, 0.f, 0.f, 0.f, 0.f};
    floatx16 accB = accA;
    const floatx16 zf16 = accA;

    for (int f = fB; f < fE; ++f) {
      const int f2 = (f + 2 < fE) ? f + 2 : fE - 1;
      short8 n0 = wA1[(size_t)((f2 * 3 + 0) * 4 + mt) * 64 + lane];
      short8 n1 = wA1[(size_t)((f2 * 3 + 1) * 4 + mt) * 64 + lane];
      short8 n2 = wA1[(size_t)((f2 * 3 + 2) * 4 + mt) * 64 + lane];
      floatx16 acfA = mfma32(a0, bqA0, zf16);
      floatx16 acfB = mfma32(a0, bqB0, zf16);
      acfA = mfma32(a1, bqA1, acfA);
      acfB = mfma32(a1, bqB1, acfB);
      acfA = mfma32(a2, bqA2, acfA);
      acfB = mfma32(a2, bqB2, acfB);
      const float sxA = xs[gA][f][d];
      const float sxB = xs[gB][f][d];
      accA += acfA * sxA;
      accB += acfB * sxB;
      a0 = p0; a1 = p1; a2 = p2;
      p0 = n0; p1 = n1; p2 = n2;
    }

    // ---- f-half partial exchange ----
    const int wid = gp2 * 4 + mt;    // 0..7, shared by the fh2 pair
    if (fh2 == 0) {
      union { short8 v; unsigned short e[8]; } w;
#pragma unroll
      for (int half = 0; half < 2; ++half) {
#pragma unroll
        for (int j = 0; j < 8; ++j) w.e[j] = bf16rne(accA[half * 8 + j]);
        Xch[(size_t)(((wid * 2 + 0) * 2 + half) * 64 + lane)] = w.v;
#pragma unroll
        for (int j = 0; j < 8; ++j) w.e[j] = bf16rne(accB[half * 8 + j]);
        Xch[(size_t)(((wid * 2 + 1) * 2 + half) * 64 + lane)] = w.v;
      }
    }
    __syncthreads();
    if (fh2 == 1) {
      union { short8 v; unsigned short e[8]; } ua, ub;
#pragma unroll
      for (int half = 0; half < 2; ++half) {
        ua.v = Xch[(size_t)(((wid * 2 + 0) * 2 + half) * 64 + lane)];
        ub.v = Xch[(size_t)(((wid * 2 + 1) * 2 + half) * 64 + lane)];
#pragma unroll
        for (int j = 0; j < 8; ++j) {
          accA[half * 8 + j] += bf16tof(ua.e[j]);
          accB[half * 8 + j] += bf16tof(ub.e[j]);
        }
      }
      // final h1 -> S_bf. Row = mt*32 + ((r&3)+8*(r>>2)+4*kg), col = g*16+d.
#pragma unroll
      for (int r = 0; r < 16; ++r) {
        const int row = (r & 3) + 8 * (r >> 2) + 4 * kg;
        S_bf[(size_t)(mt * 32 + row) * SROW + (gp2 * 2 + 0) * 32 + c32] = bf16rne(accA[r]);
        S_bf[(size_t)(mt * 32 + row) * SROW + (gp2 * 2 + 1) * 32 + c32] = bf16rne(accB[r]);
      }
    }
  }
  __syncthreads();

  // ===== phase 2a: out1[b,h] = sum_d h1 (1024 threads, one shot) =====
  {
    int h = tid & 127, g = tid >> 7;
    union { short8 v; unsigned int u[4]; } w0v, w1v;
    w0v.v = *(const short8*)&S_bf[(size_t)h * SROW + g * 16];
    w1v.v = *(const short8*)&S_bf[(size_t)h * SROW + g * 16 + 8];
    float sum = 0.f;
#pragma unroll
    for (int p = 0; p < 4; ++p) {
      sum += __uint_as_float(w0v.u[p] << 16) + __uint_as_float(w0v.u[p] & 0xFFFF0000u);
      sum += __uint_as_float(w1v.u[p] << 16) + __uint_as_float(w1v.u[p] & 0xFFFF0000u);
    }
    out[(size_t)(b0 + g) * 256 + h] = sum;
  }

  // ===== phase 2b: wave = (g, qh). U[g,(f,q)] = sum_d x[g,f,d] h1[g,q,d] =====
  // MFMA: A[m=f][k=d], B[n=q][k=d] -> C[m=f][n=q].
  // Store to Ub2[f][g][q]: imm-offset b16 stores, <=2-way banks.
  {
    const int g  = wv & 7;
    const int qh = wv >> 3;
    short8 af[3];
#pragma unroll
    for (int ft = 0; ft < 3; ++ft) {
      union { short8 v; unsigned short e[8]; } pk;
      int f = ft * 16 + col;
      if (quad < 2 && f < F0) {
        const float* xp = &xs[g][f][quad * 8];
#pragma unroll
        for (int j = 0; j < 8; ++j) pk.e[j] = bf16rne(xp[j]);
      } else {
#pragma unroll
        for (int j = 0; j < 8; ++j) pk.e[j] = 0;
      }
      af[ft] = pk.v;
    }
#pragma unroll
    for (int qi = 0; qi < 4; ++qi) {
      const int qt = qh * 4 + qi;
      short8 bq;
      if (quad < 2) {
        bq = *(const short8*)&S_bf[(size_t)(qt * 16 + col) * SROW + g * 16 + quad * 8];
      } else {
        bq = short8{0, 0, 0, 0, 0, 0, 0, 0};
      }
#pragma unroll
      for (int ft = 0; ft < 3; ++ft) {
        floatx4 c2 = mfma16(af[ft], bq, zf4);
        unsigned short* up =
            &Ub2[(size_t)(ft * 16 + quad * 4) * UFS + g * UGS + qt * 16 + col];
        if (ft < 2) {
#pragma unroll
          for (int r = 0; r < 4; ++r) up[r * UFS] = bf16rne(c2[r]);
        } else {
#pragma unroll
          for (int r = 0; r < 4; ++r)
            if (32 + quad * 4 + r < F0) up[r * UFS] = bf16rne(c2[r]);
        }
      }
    }
  }

  // ---- pre-issue phase-3's first W loads; 2b->3 barrier drain completes ----
  const int t3  = wv & 7;
  const int kh  = wv >> 3;
  const int cb0 = kh ? 20 : 0;
  const int cbN = kh ? F0 : 20;
  short8 aW[4], aX[4];
#pragma unroll
  for (int i = 0; i < 4; ++i)
    aW[i] = wA2[(size_t)((cb0 * 4 + i) * 8 + t3) * 64 + lane];
#pragma unroll
  for (int i = 0; i < 4; ++i)
    aX[i] = wA2[(size_t)(((cb0 + 1) * 4 + i) * 8 + t3) * 64 + lane];
  __syncthreads();

  // ===== phase 3: wave = (t, kh). out2 = sum_c W1frag(c) x Ufrag(c) =====
  // B-frag: k = quad*8+j over p = cb*128 + i*32 + k -> Ub2[cb][g=col][i*32+quad*8..+8]
  {
    const short8 zero8 = {0, 0, 0, 0, 0, 0, 0, 0};
    floatx4 aco[4];
#pragma unroll
    for (int i = 0; i < 4; ++i) aco[i] = zf4;
    for (int cb = cb0; cb < cbN; ++cb) {
      const int c2 = (cb + 2 < cbN) ? cb + 2 : cbN - 1;
      short8 nx[4];
#pragma unroll
      for (int i = 0; i < 4; ++i)
        nx[i] = wA2[(size_t)((c2 * 4 + i) * 8 + t3) * 64 + lane];
      const unsigned short* ubase = &Ub2[(size_t)cb * UFS + col * UGS + quad * 8];
#pragma unroll
      for (int i = 0; i < 4; ++i) {
        short8 bU = (col < 8) ? *(const short8*)(ubase + i * 32) : zero8;
        aco[i] = mfma16(aW[i], bU, aco[i]);
      }
#pragma unroll
      for (int i = 0; i < 4; ++i) { aW[i] = aX[i]; aX[i] = nx[i]; }
    }
    float v[4];
#pragma unroll
    for (int r = 0; r < 4; ++r)
      v[r] = (aco[0][r] + aco[1][r]) + (aco[2][r] + aco[3][r]);

    // k-half reduction through S32 (xs dead; stride 9 -> <=2-way banks)
    if (kh == 0 && col < 8) {
#pragma unroll
      for (int r = 0; r < 4; ++r)
        S32[(size_t)(t3 * 16 + quad * 4 + r) * 9 + col] = v[r];
    }
    __syncthreads();
    if (kh == 1 && col < 8) {
#pragma unroll
      for (int r = 0; r < 4; ++r) {
        int h = t3 * 16 + quad * 4 + r;
        out[(size_t)(b0 + col) * 256 + 128 + h] = v[r] + S32[(size_t)h * 9 + col];
      }
    }
  }
}

// ---------- fp32 last-resort fallback ----------
__global__ __launch_bounds__(128) void cin_fused_fallback(const float* __restrict__ x,
                                                          const float* __restrict__ w0,
                                                          const float* __restrict__ w1,
                                                          float* __restrict__ out) {
  __shared__ float4 xs4[F0 * D_ / 4];
  __shared__ float4 h1s4[H_ * D_ / 4];
  __shared__ float4 z4[H_ * D_ / 4];
  const int tid = threadIdx.x;
  const int b = blockIdx.x;
  const int hh = tid >> 2, dd = tid & 3, h0 = hh << 2;
  {
    const float4* xg = (const float4*)(x + (size_t)b * (F0 * D_));
    for (int i = tid; i < F0 * D_ / 4; i += 128) xs4[i] = xg[i];
  }
  __syncthreads();
  float acc[4][4];
#pragma unroll
  for (int i = 0; i < 4; ++i)
#pragma unroll
    for (int j = 0; j < 4; ++j) acc[i][j] = 0.f;
  for (int f = 0; f < F0; ++f) {
    for (int i = tid; i < F0 * D_ / 4; i += 128) {
      float4 xv = xs4[(f << 2) + (i & 3)], qv = xs4[i];
      z4[i] = make_float4(xv.x * qv.x, xv.y * qv.y, xv.z * qv.z, xv.w * qv.w);
    }
    __syncthreads();
    for (int q = 0; q < F0; ++q) {
      float4 zv = z4[(q << 2) + dd];
      int p = f * F0 + q;
      float ww[4] = {w0[(h0 + 0) * P0_ + p], w0[(h0 + 1) * P0_ + p],
                     w0[(h0 + 2) * P0_ + p], w0[(h0 + 3) * P0_ + p]};
      float zz[4] = {zv.x, zv.y, zv.z, zv.w};
#pragma unroll
      for (int hi = 0; hi < 4; ++hi)
#pragma unroll
        for (int di = 0; di < 4; ++di) acc[hi][di] += ww[hi] * zz[di];
    }
    __syncthreads();
  }
#pragma unroll
  for (int hi = 0; hi < 4; ++hi)
    h1s4[(h0 + hi) * 4 + dd] = make_float4(acc[hi][0], acc[hi][1], acc[hi][2], acc[hi][3]);
  __syncthreads();
  {
    float4 a0 = h1s4[tid * 4 + 0], a1 = h1s4[tid * 4 + 1];
    float4 a2 = h1s4[tid * 4 + 2], a3 = h1s4[tid * 4 + 3];
    out[(size_t)b * 256 + tid] = (a0.x + a0.y + a0.z + a0.w) + (a1.x + a1.y + a1.z + a1.w) +
                                 (a2.x + a2.y + a2.z + a2.w) + (a3.x + a3.y + a3.z + a3.w);
  }
#pragma unroll
  for (int i = 0; i < 4; ++i)
#pragma unroll
    for (int j = 0; j < 4; ++j) acc[i][j] = 0.f;
  for (int f = 0; f < F0; ++f) {
    for (int i = tid; i < H_ * D_ / 4; i += 128) {
      float4 xv = xs4[(f << 2) + (i & 3)], hv = h1s4[i];
      z4[i] = make_float4(xv.x * hv.x, xv.y * hv.y, xv.z * hv.z, xv.w * hv.w);
    }
    __syncthreads();
    for (int q = 0; q < H_; ++q) {
      float4 zv = z4[(q << 2) + dd];
      int p = f * H_ + q;
      float ww[4] = {w1[(h0 + 0) * P1_ + p], w1[(h0 + 1) * P1_ + p],
                     w1[(h0 + 2) * P1_ + p], w1[(h0 + 3) * P1_ + p]};
      float zz[4] = {zv.x, zv.y, zv.z, zv.w};
#pragma unroll
      for (int hi = 0; hi < 4; ++hi)
#pragma unroll
        for (int di = 0; di < 4; ++di) acc[hi][di] += ww[hi] * zz[di];
    }
    __syncthreads();
  }
#pragma unroll
  for (int hi = 0; hi < 4; ++hi)
    z4[(h0 + hi) * 4 + dd] = make_float4(acc[hi][0], acc[hi][1], acc[hi][2], acc[hi][3]);
  __syncthreads();
  {
    float4 a0 = z4[tid * 4 + 0], a1 = z4[tid * 4 + 1];
    float4 a2 = z4[tid * 4 + 2], a3 = z4[tid * 4 + 3];
    out[(size_t)b * 256 + 128 + tid] = (a0.x + a0.y + a0.z + a0.w) + (a1.x + a1.y + a1.z + a1.w) +
                                       (a2.x + a2.y + a2.z + a2.w) + (a3.x + a3.y + a3.z + a3.w);
  }
}

extern "C" void kernel_launch(void* const* d_in, const int* in_sizes, int n_in,
                              void* d_out, int out_size, void* d_ws, size_t ws_size,
                              hipStream_t stream) {
  const float* x  = (const float*)d_in[0];
  const float* w0 = (const float*)d_in[1];
  const float* w1 = (const float*)d_in[2];
  float* out = (float*)d_out;

  const size_t nfr    = (size_t)(NF1 + NF2) * 64;   // 109824 (frag,lane) pairs
  const size_t wbytes = nfr * sizeof(short8);       // ~1.76 MB

  if (ws_size >= wbytes) {
    short8* wA1 = (short8*)d_ws;
    short8* wA2 = wA1 + (size_t)NF1 * 64;
    pack_w_kernel<<<(int)((nfr + 255) / 256), 256, 0, stream>>>(w0, w1, wA1, wA2);
    cin_fused<<<256, 1024, 0, stream>>>(x, wA1, wA2, out);
  } else {
    cin_fused_fallback<<<2048, 128, 0, stream>>>(x, w0, w1, out);
  }
}